// Round 5
// baseline (118.217 us; speedup 1.0000x reference)
//
#include <hip/hip_runtime.h>
#include <cmath>
#include <cstdint>

// Problem: B=2, C=32, Z=4, E=2, N=4096. One candidate point per lattice cell,
// cell pitch (0.78125, 0.78125, 0.75); offsets in [0,1) cell units.
// => dist < ele_d (0.74 / 0.528) pairs confined to 3x3x3 cells.
// => any point outside the xy +-2 window is >= 1.5625*(1-eps) away: a
//    neighborhood argmin < GUARD=1.4999 is provably the global argmin.
// => for NMS adjacency: pairs >=2 z-cells apart have dz >= 0.75*(1-2^-23)
//    => d2 >= 0.5624998 > se(0.74)=0.5476 — restrain/keep need z+-1 only.
//
// Ladder: 4 kernels 77.9us -> fused+LDS 70.0 (kernel 19.6us) -> 2 blk/CU
// 64.8 (kernel 14.4us). Still latency-floored (stage loads are HBM-cold:
// the harness' 268MB re-poison fill evicts L2 every iteration). R5: max
// occupancy — 1024 blocks x 512 thr = 4 blk/CU = 32 waves/CU (8/SIMD),
// interior 16 rows/block, every phase <=1 item/thread; early global-store
// issue (TPOS at entry, PPOS during phase A) to hide store latency.
namespace {
constexpr int NPT  = 4096;

// output offsets (floats), reference return order
constexpr int O_PPOS  = 0;
constexpr int O_MASKP = 49152;
constexpr int O_KEEP  = 65536;
constexpr int O_TPOS  = 81920;
constexpr int O_MASKT = 131072;
constexpr int O_TPT   = 147456;
constexpr int O_TPP   = 163840;
constexpr int O_TPTN  = 180224;
constexpr int O_TPPN  = 196608;

constexpr float GUARD = 1.4999f;
} // namespace

__device__ __forceinline__ unsigned long long shfl_xor_u64(unsigned long long v, int m) {
    unsigned lo = (unsigned)v, hi = (unsigned)(v >> 32);
    lo = __shfl_xor(lo, m); hi = __shfl_xor(hi, m);
    return ((unsigned long long)hi << 32) | lo;
}

// position from raw input + cell index — bit-identical everywhere (contract off,
// lattice constants 25/32 and 3/4 are exactly representable)
__device__ __forceinline__ float3 cellpos(float4 p, int n) {
#pragma clang fp contract(off)
    float fx = (float)(n >> 7), fy = (float)((n >> 2) & 31), fz = (float)(n & 3);
    float3 r;
    r.x = (p.x + fx) * 0.78125f;
    r.y = (p.y + fy) * 0.78125f;
    r.z = (p.z + fz) * 0.75f;
    return r;
}
__device__ __forceinline__ float dist2(float3 a, float3 b) {
#pragma clang fp contract(off)
    float dx = a.x - b.x, dy = a.y - b.y, dz = a.z - b.z;
    float d2 = dx * dx + dy * dy;
    return d2 + dz * dz;   // numpy sum order: (x+y)+z
}

// exact restrain count of slice-local point pn, reading GLOBAL pred.
// Only used by the never-taken exact fallback.
__device__ __forceinline__ unsigned restrain_of(const float4* __restrict__ pred,
                                                int base4, int pn, float se) {
#pragma clang fp contract(off)
    float4 p = pred[base4 + pn * 2];
    if (!(p.w > 0.5f)) return 0u;
    float3 pj = cellpos(p, pn);
    int gx = pn >> 7, gy = (pn >> 2) & 31;
    unsigned c = 0;
    for (int q = 0; q < 9; ++q) {
        int nx = gx + q / 3 - 1, ny = gy + q % 3 - 1;
        if ((unsigned)nx > 31u || (unsigned)ny > 31u) continue;
        int nb = nx * 128 + ny * 4;
#pragma unroll
        for (int nz = 0; nz < 4; ++nz) {
            int ni = nb + nz;
            float4 pi = pred[base4 + ni * 2];
            float3 qi = cellpos(pi, ni);
            float d2 = dist2(pj, qi);
            bool prec = (pi.w > p.w) || ((pi.w == p.w) && (ni < pn));
            if ((pi.w > 0.5f) && (d2 < se) && prec) c++;
        }
    }
    return c;
}

// exact keep decision of slice-local point k (suppression on top of restrain),
// reading GLOBAL pred. Only called from the rare fallback path.
__device__ __noinline__ bool keep_of(const float4* __restrict__ pred,
                                     int base4, int k, float se) {
#pragma clang fp contract(off)
    float4 p = pred[base4 + k * 2];
    if (!(p.w > 0.5f)) return false;
    float3 pj = cellpos(p, k);
    int gx = k >> 7, gy = (k >> 2) & 31;
    for (int q = 0; q < 9; ++q) {
        int nx = gx + q / 3 - 1, ny = gy + q % 3 - 1;
        if ((unsigned)nx > 31u || (unsigned)ny > 31u) continue;
        int nb = nx * 128 + ny * 4;
        for (int nz = 0; nz < 4; ++nz) {
            int ni = nb + nz;
            float4 pi = pred[base4 + ni * 2];
            float3 qi = cellpos(pi, ni);
            float d2 = dist2(pj, qi);
            bool prec = (pi.w > p.w) || ((pi.w == p.w) && (ni < k));
            if ((pi.w > 0.5f) && (d2 < se) && prec &&
                restrain_of(pred, base4, ni, se) == 0u)
                return false;
        }
    }
    return true;
}

// ---------------------------------------------------------------------------
// Single fused kernel. One block per (s, gx, gy-eighth): 4*32*8 = 1024 blocks,
// 512 threads -> 4 blocks/CU = 32 waves/CU (8/SIMD, the HW max).
// Stage : pred window [gx-4,gx+4] x [gy0-4,gy0+7] x z (9x12x4=432) -> LDS,
//         position pre-projected, conf in .w; OOB cells get conf=-1 which
//         every later predicate rejects, so phase loops are bounds-check-free.
// Phase A: restrain over 7x10x4=280 -> LDS uchar (z+-1 comps only); idle
//          threads 448..463 write PPOS/MASKP for the 16 interior rows.
// Phase B: keep over 5x8x4=160 -> LDS uchar (z+-1); interior writes O_KEEP.
// Phase C: match (both variants) for the 16 interior rows, 32 threads/row,
//          5x5 xy window x full z from LDS, inline exact (global) fallback.
__global__ void __launch_bounds__(512, 8) k_all(const float4* __restrict__ pred,
                                                const float4* __restrict__ tgt,
                                                float* __restrict__ out,
                                                float s0, float s1) {
#pragma clang fp contract(off)
    __shared__ float4 pp[9 * 12 * 4];             // (pos.xyz, conf) 6912 B
    __shared__ unsigned char restr[7 * 10 * 4];   // 280
    __shared__ unsigned char keepl[5 * 8 * 4];    // 160
    int bid = blockIdx.x;
    int gy0 = (bid & 7) << 2, gx = (bid >> 3) & 31, s = bid >> 8;
    int b = s >> 1, e = s & 1;
    int base4 = b * 8192 + e;
    float se = (s & 1) ? s1 : s0;
    int t = (int)threadIdx.x;

    // phase-C row of this thread; tgt prefetched at entry so its global
    // latency hides under stage/A/B.
    int rr = t >> 5, hh = t & 31;
    int gyy_c = rr >> 2, z_c = rr & 3;
    int n_c = (gx << 7) + ((gy0 + gyy_c) << 2) + z_c;
    int row_c = s * NPT + n_c;
    float4 t4 = tgt[base4 + n_c * 2];
    float3 tj = cellpos(t4, n_c);
    bool tv = t4.w > 0.5f;
    if (hh == 0) {                                 // early store issue
        out[O_TPOS + row_c * 3 + 0] = tj.x;
        out[O_TPOS + row_c * 3 + 1] = tj.y;
        out[O_TPOS + row_c * 3 + 2] = tj.z;
        out[O_MASKT + row_c] = tv ? 1.0f : 0.0f;
    }

    // ---- stage pred window -> LDS (1 load for t<432)
    if (t < 432) {
        int rx = t / 48, rem = t - rx * 48, ry = rem >> 2, z = rem & 3;
        int px = gx + rx - 4, py = gy0 + ry - 4;
        float4 v = {0.0f, 0.0f, 0.0f, -1.0f};
        if ((unsigned)px < 32u && (unsigned)py < 32u) {
            int pn = px * 128 + py * 4 + z;
            float4 p = pred[base4 + pn * 2];
            float3 c = cellpos(p, pn);
            v.x = c.x; v.y = c.y; v.z = c.z; v.w = p.w;
        }
        pp[t] = v;
    }
    __syncthreads();

    // ---- phase A: restrain halo (280 pts, 1/thread), z+-1 comps
    if (t < 280) {
        int ax = t / 40, rem = t - ax * 40, ay = rem >> 2, z = rem & 3;
        int px = gx + ax - 3, py = gy0 + ay - 3;
        float4 p = pp[((ax + 1) * 12 + (ay + 1)) * 4 + z];
        unsigned c = 0;
        if (p.w > 0.5f) {                          // OOB center: conf=-1 -> skip
            int pn = px * 128 + py * 4 + z;
            float3 pj = {p.x, p.y, p.z};
#pragma unroll
            for (int q = 0; q < 9; ++q) {
                int dx = q / 3 - 1, dy = q % 3 - 1;
                int nb = (px + dx) * 128 + (py + dy) * 4;
                const float4* pc = &pp[((ax + 1 + dx) * 12 + (ay + 1 + dy)) * 4];
#pragma unroll
                for (int dz = -1; dz <= 1; ++dz) {
                    int nz = z + dz;
                    int nzc = nz < 0 ? 0 : (nz > 3 ? 3 : nz);
                    float4 pi = pc[nzc];
                    int ni = nb + nz;
                    float3 qi = {pi.x, pi.y, pi.z};
                    float d2 = dist2(pj, qi);
                    bool zok = (unsigned)nz < 4u;
                    bool prec = (pi.w > p.w) || ((pi.w == p.w) && (ni < pn));
                    if (zok && (pi.w > 0.5f) && (d2 < se) && prec) c++;
                }
            }
        }
        restr[t] = (unsigned char)c;               // max 27, fits uchar
    } else if (t >= 448 && t < 464) {              // PPOS/MASKP early stores
        int ir = t - 448;
        int gyy = ir >> 2, z = ir & 3;
        int n = (gx << 7) + ((gy0 + gyy) << 2) + z;
        int row = s * NPT + n;
        float4 p = pp[(48 + (gyy + 4)) * 4 + z];   // rx=4 -> (4*12 + ry)*4+z
        out[O_PPOS + row * 3 + 0] = p.x;
        out[O_PPOS + row * 3 + 1] = p.y;
        out[O_PPOS + row * 3 + 2] = p.z;
        out[O_MASKP + row] = (p.w > 0.5f) ? 1.0f : 0.0f;
    }
    __syncthreads();

    // ---- phase B: keep halo (160 pts, 1/thread), z+-1; interior writes keep
    if (t < 160) {
        int kx = t / 32, rem = t - kx * 32, ky = rem >> 2, z = rem & 3;
        int px = gx + kx - 2, py = gy0 + ky - 2;
        float4 p = pp[((kx + 2) * 12 + (ky + 2)) * 4 + z];
        bool valid = p.w > 0.5f;
        int pn = px * 128 + py * 4 + z;
        unsigned any = 0;
        if (valid) {
            float3 pj = {p.x, p.y, p.z};
#pragma unroll
            for (int q = 0; q < 9; ++q) {
                int dx = q / 3 - 1, dy = q % 3 - 1;
                int nb = (px + dx) * 128 + (py + dy) * 4;
                const float4* pc = &pp[((kx + 2 + dx) * 12 + (ky + 2 + dy)) * 4];
                const unsigned char* lr =
                    &restr[((kx + 1 + dx) * 10 + (ky + 1 + dy)) * 4];
#pragma unroll
                for (int dz = -1; dz <= 1; ++dz) {
                    int nz = z + dz;
                    int nzc = nz < 0 ? 0 : (nz > 3 ? 3 : nz);
                    float4 pi = pc[nzc];
                    int ni = nb + nz;
                    float3 qi = {pi.x, pi.y, pi.z};
                    float d2 = dist2(pj, qi);
                    bool zok = (unsigned)nz < 4u;
                    bool prec = (pi.w > p.w) || ((pi.w == p.w) && (ni < pn));
                    if (zok && (pi.w > 0.5f) && (lr[nzc] == 0) && (d2 < se) && prec)
                        any = 1u;
                }
            }
        }
        bool keep = valid && (any == 0);
        keepl[t] = keep ? 1 : 0;
        if (kx == 2 && ky >= 2 && ky < 6) {        // interior: always in-bounds
            int row = s * NPT + pn;
            out[O_KEEP + row] = keep ? 1.0f : 0.0f;
        }
    }
    __syncthreads();

    // ---- phase C: match, 16 rows x 32 threads
    int gyy = gyy_c, h = hh;
    int gy = gy0 + gyy;
    int row = row_c;
    if (!tv) {   // group-uniform early out (all-inf row -> masks 0, idx 0)
        if (h == 0) {
            out[O_TPT + row] = 0.0f; out[O_TPTN + row] = 0.0f;
            out[O_TPP + row] = 0.0f; out[O_TPPN + row] = 0.0f;
        }
        return;
    }
    unsigned long long bs = ~0ull, bn = ~0ull;
    unsigned as_ = 0, an_ = 0;
    if (h < 25) {                                  // one 5x5 cell per lane
        int dx = h / 5 - 2, dy = h % 5 - 2;
        int nb = (gx + dx) * 128 + (gy + dy) * 4;
        const float4* pc = &pp[((dx + 4) * 12 + (gyy + dy + 4)) * 4];
        const unsigned char* lk = &keepl[((dx + 2) * 8 + (gyy + dy + 2)) * 4];
#pragma unroll
        for (int nz = 0; nz < 4; ++nz) {
            float4 pi = pc[nz];
            int ni = nb + nz;
            float3 qi = {pi.x, pi.y, pi.z};
            float d2 = dist2(tj, qi);
            float dist = sqrtf(d2);
            unsigned long long enc =
                ((unsigned long long)__float_as_uint(dist) << 32) | (unsigned)ni;
            if (pi.w > 0.5f) { if (enc < bs) bs = enc; if (d2 < se) as_ = 1u; }
            if (lk[nz]) { if (enc < bn) bn = enc; if (d2 < se) an_ = 1u; }
        }
    }
    for (int m = 1; m < 32; m <<= 1) {             // combine across the 32-group
        unsigned long long o = shfl_xor_u64(bs, m); if (o < bs) bs = o;
        o = shfl_xor_u64(bn, m); if (o < bn) bn = o;
        as_ |= __shfl_xor(as_, m);
        an_ |= __shfl_xor(an_, m);
    }
    // empty best -> hi word 0xFFFFFFFF = NaN -> compare false -> fallback
    bool acc_s = __uint_as_float((unsigned)(bs >> 32)) < GUARD;
    bool acc_n = __uint_as_float((unsigned)(bn >> 32)) < GUARD;
    if (!(acc_s && acc_n)) {
        // exact full-row fallback by this 32-group (p ~ 1e-11, never observed;
        // bit-equal to window result when the window would have accepted).
        unsigned long long fs = ~0ull, fn = ~0ull;
        for (int k = h; k < NPT; k += 32) {
            float4 pi = pred[base4 + k * 2];
            float3 qi = cellpos(pi, k);
            float d2 = dist2(tj, qi);
            float dist = sqrtf(d2);
            unsigned long long enc =
                ((unsigned long long)__float_as_uint(dist) << 32) | (unsigned)k;
            if (pi.w > 0.5f && enc < fs) fs = enc;
            if (enc < fn && keep_of(pred, base4, k, se)) fn = enc;
        }
        for (int m = 1; m < 32; m <<= 1) {
            unsigned long long o = shfl_xor_u64(fs, m); if (o < fs) fs = o;
            o = shfl_xor_u64(fn, m); if (o < fn) fn = o;
        }
        bs = fs; bn = fn;
    }
    if (h == 0) {
        out[O_TPT + row]  = as_ ? 1.0f : 0.0f;
        out[O_TPTN + row] = an_ ? 1.0f : 0.0f;
        out[O_TPP + row]  = (float)((bs == ~0ull) ? 0u : (unsigned)(bs & 0xffffffffull));
        out[O_TPPN + row] = (float)((bn == ~0ull) ? 0u : (unsigned)(bn & 0xffffffffull));
    }
}

// ---------------------------------------------------------------------------
// host: smallest f with sqrtf(f) >= t, so (d2 < f) <=> (sqrtf(d2) < t) bit-exactly.
static float sq_boundary(float t) {
    float f = (float)((double)t * (double)t);
    while (sqrtf(f) >= t) f = nextafterf(f, 0.0f);
    while (sqrtf(f) < t)  f = nextafterf(f, __builtin_inff());
    return f;
}

extern "C" void kernel_launch(void* const* d_in, const int* in_sizes, int n_in,
                              void* d_out, int out_size, void* d_ws, size_t ws_size,
                              hipStream_t stream) {
    (void)in_sizes; (void)n_in; (void)out_size; (void)d_ws; (void)ws_size;
    const float4* pred = (const float4*)d_in[0];
    const float4* tgt  = (const float4*)d_in[1];
    float* out = (float*)d_out;

    float s0 = sq_boundary(0.74f);    // ELE_D[0]
    float s1 = sq_boundary(0.528f);   // ELE_D[1]

    k_all<<<dim3(1024), dim3(512), 0, stream>>>(pred, tgt, out, s0, s1);
}

// Round 6
// 78.849 us; speedup vs baseline: 1.4993x; 1.4993x over previous
//
#include <hip/hip_runtime.h>
#include <cmath>
#include <cstdint>

// Problem: B=2, C=32, Z=4, E=2, N=4096. One candidate point per lattice cell,
// cell pitch (0.78125, 0.78125, 0.75); offsets in [0,1) cell units.
// => dist < ele_d (0.74 / 0.528) pairs confined to 3x3x3 cells.
// => any point outside the xy +-2 window is >= 1.5625*(1-eps) away: a
//    neighborhood argmin < GUARD=1.4999 is provably the global argmin.
// => for NMS adjacency: pairs >=2 z-cells apart have dz >= 0.75*(1-2^-23)
//    => d2 >= 0.5624998 > se(0.74)=0.5476 — restrain/keep need z+-1 only.
//
// Ladder: 4 kernels 77.9us -> fused+LDS 70.0 (kernel 19.6us) -> 2 blk/CU
// 64.8 (kernel 14.4us) -> R5 118us REGRESSION: __launch_bounds__(512,8)
// forced VGPR 36->32, spilling ~180B/thread to scratch (FETCH 71MB,
// WRITE 95MB — pure spill traffic). R6: same 1024-block structure with
// launch_bounds(512,4) — 36-48 VGPR < 64 means the HW reaches 4 blk/CU
// (32 waves/CU) through ACTUAL usage; never coerce the allocator.
namespace {
constexpr int NPT  = 4096;

// output offsets (floats), reference return order
constexpr int O_PPOS  = 0;
constexpr int O_MASKP = 49152;
constexpr int O_KEEP  = 65536;
constexpr int O_TPOS  = 81920;
constexpr int O_MASKT = 131072;
constexpr int O_TPT   = 147456;
constexpr int O_TPP   = 163840;
constexpr int O_TPTN  = 180224;
constexpr int O_TPPN  = 196608;

constexpr float GUARD = 1.4999f;
} // namespace

__device__ __forceinline__ unsigned long long shfl_xor_u64(unsigned long long v, int m) {
    unsigned lo = (unsigned)v, hi = (unsigned)(v >> 32);
    lo = __shfl_xor(lo, m); hi = __shfl_xor(hi, m);
    return ((unsigned long long)hi << 32) | lo;
}

// position from raw input + cell index — bit-identical everywhere (contract off,
// lattice constants 25/32 and 3/4 are exactly representable)
__device__ __forceinline__ float3 cellpos(float4 p, int n) {
#pragma clang fp contract(off)
    float fx = (float)(n >> 7), fy = (float)((n >> 2) & 31), fz = (float)(n & 3);
    float3 r;
    r.x = (p.x + fx) * 0.78125f;
    r.y = (p.y + fy) * 0.78125f;
    r.z = (p.z + fz) * 0.75f;
    return r;
}
__device__ __forceinline__ float dist2(float3 a, float3 b) {
#pragma clang fp contract(off)
    float dx = a.x - b.x, dy = a.y - b.y, dz = a.z - b.z;
    float d2 = dx * dx + dy * dy;
    return d2 + dz * dz;   // numpy sum order: (x+y)+z
}

// exact restrain count of slice-local point pn, reading GLOBAL pred.
// Only used by the never-taken exact fallback.
__device__ __forceinline__ unsigned restrain_of(const float4* __restrict__ pred,
                                                int base4, int pn, float se) {
#pragma clang fp contract(off)
    float4 p = pred[base4 + pn * 2];
    if (!(p.w > 0.5f)) return 0u;
    float3 pj = cellpos(p, pn);
    int gx = pn >> 7, gy = (pn >> 2) & 31;
    unsigned c = 0;
    for (int q = 0; q < 9; ++q) {
        int nx = gx + q / 3 - 1, ny = gy + q % 3 - 1;
        if ((unsigned)nx > 31u || (unsigned)ny > 31u) continue;
        int nb = nx * 128 + ny * 4;
#pragma unroll
        for (int nz = 0; nz < 4; ++nz) {
            int ni = nb + nz;
            float4 pi = pred[base4 + ni * 2];
            float3 qi = cellpos(pi, ni);
            float d2 = dist2(pj, qi);
            bool prec = (pi.w > p.w) || ((pi.w == p.w) && (ni < pn));
            if ((pi.w > 0.5f) && (d2 < se) && prec) c++;
        }
    }
    return c;
}

// exact keep decision of slice-local point k (suppression on top of restrain),
// reading GLOBAL pred. Only called from the rare fallback path.
__device__ __noinline__ bool keep_of(const float4* __restrict__ pred,
                                     int base4, int k, float se) {
#pragma clang fp contract(off)
    float4 p = pred[base4 + k * 2];
    if (!(p.w > 0.5f)) return false;
    float3 pj = cellpos(p, k);
    int gx = k >> 7, gy = (k >> 2) & 31;
    for (int q = 0; q < 9; ++q) {
        int nx = gx + q / 3 - 1, ny = gy + q % 3 - 1;
        if ((unsigned)nx > 31u || (unsigned)ny > 31u) continue;
        int nb = nx * 128 + ny * 4;
        for (int nz = 0; nz < 4; ++nz) {
            int ni = nb + nz;
            float4 pi = pred[base4 + ni * 2];
            float3 qi = cellpos(pi, ni);
            float d2 = dist2(pj, qi);
            bool prec = (pi.w > p.w) || ((pi.w == p.w) && (ni < k));
            if ((pi.w > 0.5f) && (d2 < se) && prec &&
                restrain_of(pred, base4, ni, se) == 0u)
                return false;
        }
    }
    return true;
}

// ---------------------------------------------------------------------------
// Single fused kernel. One block per (s, gx, gy-eighth): 4*32*8 = 1024 blocks,
// 512 threads. VGPR ~36-48 (<64) + LDS 7.5KB -> HW co-schedules 4 blocks/CU
// = 32 waves/CU without launch_bounds coercion (R5 lesson: forcing 8
// waves/EU throttled VGPR to 32 and spilled 170MB to scratch).
// Stage : pred window [gx-4,gx+4] x [gy0-4,gy0+7] x z (9x12x4=432) -> LDS,
//         position pre-projected, conf in .w; OOB cells get conf=-1 which
//         every later predicate rejects, so phase loops are bounds-check-free.
// Phase A: restrain over 7x10x4=280 -> LDS uchar (z+-1 comps only); idle
//          threads 448..463 write PPOS/MASKP for the 16 interior rows.
// Phase B: keep over 5x8x4=160 -> LDS uchar (z+-1); interior writes O_KEEP.
// Phase C: match (both variants) for the 16 interior rows, 32 threads/row,
//          5x5 xy window x full z from LDS, inline exact (global) fallback.
__global__ void __launch_bounds__(512, 4) k_all(const float4* __restrict__ pred,
                                                const float4* __restrict__ tgt,
                                                float* __restrict__ out,
                                                float s0, float s1) {
#pragma clang fp contract(off)
    __shared__ float4 pp[9 * 12 * 4];             // (pos.xyz, conf) 6912 B
    __shared__ unsigned char restr[7 * 10 * 4];   // 280
    __shared__ unsigned char keepl[5 * 8 * 4];    // 160
    int bid = blockIdx.x;
    int gy0 = (bid & 7) << 2, gx = (bid >> 3) & 31, s = bid >> 8;
    int b = s >> 1, e = s & 1;
    int base4 = b * 8192 + e;
    float se = (s & 1) ? s1 : s0;
    int t = (int)threadIdx.x;

    // phase-C row of this thread; tgt prefetched at entry so its global
    // latency hides under stage/A/B.
    int rr = t >> 5, hh = t & 31;
    int gyy_c = rr >> 2, z_c = rr & 3;
    int n_c = (gx << 7) + ((gy0 + gyy_c) << 2) + z_c;
    int row_c = s * NPT + n_c;
    float4 t4 = tgt[base4 + n_c * 2];
    float3 tj = cellpos(t4, n_c);
    bool tv = t4.w > 0.5f;
    if (hh == 0) {                                 // early store issue
        out[O_TPOS + row_c * 3 + 0] = tj.x;
        out[O_TPOS + row_c * 3 + 1] = tj.y;
        out[O_TPOS + row_c * 3 + 2] = tj.z;
        out[O_MASKT + row_c] = tv ? 1.0f : 0.0f;
    }

    // ---- stage pred window -> LDS (1 load for t<432)
    if (t < 432) {
        int rx = t / 48, rem = t - rx * 48, ry = rem >> 2, z = rem & 3;
        int px = gx + rx - 4, py = gy0 + ry - 4;
        float4 v = {0.0f, 0.0f, 0.0f, -1.0f};
        if ((unsigned)px < 32u && (unsigned)py < 32u) {
            int pn = px * 128 + py * 4 + z;
            float4 p = pred[base4 + pn * 2];
            float3 c = cellpos(p, pn);
            v.x = c.x; v.y = c.y; v.z = c.z; v.w = p.w;
        }
        pp[t] = v;
    }
    __syncthreads();

    // ---- phase A: restrain halo (280 pts, 1/thread), z+-1 comps
    if (t < 280) {
        int ax = t / 40, rem = t - ax * 40, ay = rem >> 2, z = rem & 3;
        int px = gx + ax - 3, py = gy0 + ay - 3;
        float4 p = pp[((ax + 1) * 12 + (ay + 1)) * 4 + z];
        unsigned c = 0;
        if (p.w > 0.5f) {                          // OOB center: conf=-1 -> skip
            int pn = px * 128 + py * 4 + z;
            float3 pj = {p.x, p.y, p.z};
#pragma unroll
            for (int q = 0; q < 9; ++q) {
                int dx = q / 3 - 1, dy = q % 3 - 1;
                int nb = (px + dx) * 128 + (py + dy) * 4;
                const float4* pc = &pp[((ax + 1 + dx) * 12 + (ay + 1 + dy)) * 4];
#pragma unroll
                for (int dz = -1; dz <= 1; ++dz) {
                    int nz = z + dz;
                    int nzc = nz < 0 ? 0 : (nz > 3 ? 3 : nz);
                    float4 pi = pc[nzc];
                    int ni = nb + nz;
                    float3 qi = {pi.x, pi.y, pi.z};
                    float d2 = dist2(pj, qi);
                    bool zok = (unsigned)nz < 4u;
                    bool prec = (pi.w > p.w) || ((pi.w == p.w) && (ni < pn));
                    if (zok && (pi.w > 0.5f) && (d2 < se) && prec) c++;
                }
            }
        }
        restr[t] = (unsigned char)c;               // max 27, fits uchar
    } else if (t >= 448 && t < 464) {              // PPOS/MASKP early stores
        int ir = t - 448;
        int gyy = ir >> 2, z = ir & 3;
        int n = (gx << 7) + ((gy0 + gyy) << 2) + z;
        int row = s * NPT + n;
        float4 p = pp[(48 + (gyy + 4)) * 4 + z];   // rx=4 -> (4*12 + ry)*4+z
        out[O_PPOS + row * 3 + 0] = p.x;
        out[O_PPOS + row * 3 + 1] = p.y;
        out[O_PPOS + row * 3 + 2] = p.z;
        out[O_MASKP + row] = (p.w > 0.5f) ? 1.0f : 0.0f;
    }
    __syncthreads();

    // ---- phase B: keep halo (160 pts, 1/thread), z+-1; interior writes keep
    if (t < 160) {
        int kx = t / 32, rem = t - kx * 32, ky = rem >> 2, z = rem & 3;
        int px = gx + kx - 2, py = gy0 + ky - 2;
        float4 p = pp[((kx + 2) * 12 + (ky + 2)) * 4 + z];
        bool valid = p.w > 0.5f;
        int pn = px * 128 + py * 4 + z;
        unsigned any = 0;
        if (valid) {
            float3 pj = {p.x, p.y, p.z};
#pragma unroll
            for (int q = 0; q < 9; ++q) {
                int dx = q / 3 - 1, dy = q % 3 - 1;
                int nb = (px + dx) * 128 + (py + dy) * 4;
                const float4* pc = &pp[((kx + 2 + dx) * 12 + (ky + 2 + dy)) * 4];
                const unsigned char* lr =
                    &restr[((kx + 1 + dx) * 10 + (ky + 1 + dy)) * 4];
#pragma unroll
                for (int dz = -1; dz <= 1; ++dz) {
                    int nz = z + dz;
                    int nzc = nz < 0 ? 0 : (nz > 3 ? 3 : nz);
                    float4 pi = pc[nzc];
                    int ni = nb + nz;
                    float3 qi = {pi.x, pi.y, pi.z};
                    float d2 = dist2(pj, qi);
                    bool zok = (unsigned)nz < 4u;
                    bool prec = (pi.w > p.w) || ((pi.w == p.w) && (ni < pn));
                    if (zok && (pi.w > 0.5f) && (lr[nzc] == 0) && (d2 < se) && prec)
                        any = 1u;
                }
            }
        }
        bool keep = valid && (any == 0);
        keepl[t] = keep ? 1 : 0;
        if (kx == 2 && ky >= 2 && ky < 6) {        // interior: always in-bounds
            int row = s * NPT + pn;
            out[O_KEEP + row] = keep ? 1.0f : 0.0f;
        }
    }
    __syncthreads();

    // ---- phase C: match, 16 rows x 32 threads
    int gyy = gyy_c, h = hh;
    int gy = gy0 + gyy;
    int row = row_c;
    if (!tv) {   // group-uniform early out (all-inf row -> masks 0, idx 0)
        if (h == 0) {
            out[O_TPT + row] = 0.0f; out[O_TPTN + row] = 0.0f;
            out[O_TPP + row] = 0.0f; out[O_TPPN + row] = 0.0f;
        }
        return;
    }
    unsigned long long bs = ~0ull, bn = ~0ull;
    unsigned as_ = 0, an_ = 0;
    if (h < 25) {                                  // one 5x5 cell per lane
        int dx = h / 5 - 2, dy = h % 5 - 2;
        int nb = (gx + dx) * 128 + (gy + dy) * 4;
        const float4* pc = &pp[((dx + 4) * 12 + (gyy + dy + 4)) * 4];
        const unsigned char* lk = &keepl[((dx + 2) * 8 + (gyy + dy + 2)) * 4];
#pragma unroll
        for (int nz = 0; nz < 4; ++nz) {
            float4 pi = pc[nz];
            int ni = nb + nz;
            float3 qi = {pi.x, pi.y, pi.z};
            float d2 = dist2(tj, qi);
            float dist = sqrtf(d2);
            unsigned long long enc =
                ((unsigned long long)__float_as_uint(dist) << 32) | (unsigned)ni;
            if (pi.w > 0.5f) { if (enc < bs) bs = enc; if (d2 < se) as_ = 1u; }
            if (lk[nz]) { if (enc < bn) bn = enc; if (d2 < se) an_ = 1u; }
        }
    }
    for (int m = 1; m < 32; m <<= 1) {             // combine across the 32-group
        unsigned long long o = shfl_xor_u64(bs, m); if (o < bs) bs = o;
        o = shfl_xor_u64(bn, m); if (o < bn) bn = o;
        as_ |= __shfl_xor(as_, m);
        an_ |= __shfl_xor(an_, m);
    }
    // empty best -> hi word 0xFFFFFFFF = NaN -> compare false -> fallback
    bool acc_s = __uint_as_float((unsigned)(bs >> 32)) < GUARD;
    bool acc_n = __uint_as_float((unsigned)(bn >> 32)) < GUARD;
    if (!(acc_s && acc_n)) {
        // exact full-row fallback by this 32-group (p ~ 1e-11, never observed;
        // bit-equal to window result when the window would have accepted).
        unsigned long long fs = ~0ull, fn = ~0ull;
        for (int k = h; k < NPT; k += 32) {
            float4 pi = pred[base4 + k * 2];
            float3 qi = cellpos(pi, k);
            float d2 = dist2(tj, qi);
            float dist = sqrtf(d2);
            unsigned long long enc =
                ((unsigned long long)__float_as_uint(dist) << 32) | (unsigned)k;
            if (pi.w > 0.5f && enc < fs) fs = enc;
            if (enc < fn && keep_of(pred, base4, k, se)) fn = enc;
        }
        for (int m = 1; m < 32; m <<= 1) {
            unsigned long long o = shfl_xor_u64(fs, m); if (o < fs) fs = o;
            o = shfl_xor_u64(fn, m); if (o < fn) fn = o;
        }
        bs = fs; bn = fn;
    }
    if (h == 0) {
        out[O_TPT + row]  = as_ ? 1.0f : 0.0f;
        out[O_TPTN + row] = an_ ? 1.0f : 0.0f;
        out[O_TPP + row]  = (float)((bs == ~0ull) ? 0u : (unsigned)(bs & 0xffffffffull));
        out[O_TPPN + row] = (float)((bn == ~0ull) ? 0u : (unsigned)(bn & 0xffffffffull));
    }
}

// ---------------------------------------------------------------------------
// host: smallest f with sqrtf(f) >= t, so (d2 < f) <=> (sqrtf(d2) < t) bit-exactly.
static float sq_boundary(float t) {
    float f = (float)((double)t * (double)t);
    while (sqrtf(f) >= t) f = nextafterf(f, 0.0f);
    while (sqrtf(f) < t)  f = nextafterf(f, __builtin_inff());
    return f;
}

extern "C" void kernel_launch(void* const* d_in, const int* in_sizes, int n_in,
                              void* d_out, int out_size, void* d_ws, size_t ws_size,
                              hipStream_t stream) {
    (void)in_sizes; (void)n_in; (void)out_size; (void)d_ws; (void)ws_size;
    const float4* pred = (const float4*)d_in[0];
    const float4* tgt  = (const float4*)d_in[1];
    float* out = (float*)d_out;

    float s0 = sq_boundary(0.74f);    // ELE_D[0]
    float s1 = sq_boundary(0.528f);   // ELE_D[1]

    k_all<<<dim3(1024), dim3(512), 0, stream>>>(pred, tgt, out, s0, s1);
}

// Round 7
// 64.972 us; speedup vs baseline: 1.8195x; 1.2136x over previous
//
#include <hip/hip_runtime.h>
#include <cmath>
#include <cstdint>

// Problem: B=2, C=32, Z=4, E=2, N=4096. One candidate point per lattice cell,
// cell pitch (0.78125, 0.78125, 0.75); offsets in [0,1) cell units.
// => dist < ele_d (0.74 / 0.528) pairs confined to 3x3x3 cells.
// => any point outside the xy +-2 window is >= 1.5625*(1-eps) away: a
//    neighborhood argmin < GUARD=1.4999 is provably the global argmin.
// => for NMS adjacency: pairs >=2 z-cells apart have dz >= 0.75*(1-2^-23)
//    => d2 >= 0.5624998 > se(0.74)=0.5476 — restrain/keep need z+-1 only.
//
// Ladder: 77.9 (4 kernels) -> 70.0 (fused+LDS) -> 64.8 (R4: 512blk x 512thr,
// 2 blk/CU) -> R5 118 (launch_bounds(512,8) VGPR-throttle -> 170MB spill)
// -> R6 78.8 (1024 blk needs 4 blk/CU co-residency; if VGPR>64 it runs 2
// sequential rounds = 2x R4). R7: R4 skeleton (512 blocks -> only 2 blk/CU
// needed, robust for any VGPR<=128) with a 2x4 gx*gy interior retile that
// amortizes the +-4 x-halo over 2 columns: stage 576->480, A 392->320,
// B 240->192, C unchanged.
namespace {
constexpr int NPT  = 4096;

// output offsets (floats), reference return order
constexpr int O_PPOS  = 0;
constexpr int O_MASKP = 49152;
constexpr int O_KEEP  = 65536;
constexpr int O_TPOS  = 81920;
constexpr int O_MASKT = 131072;
constexpr int O_TPT   = 147456;
constexpr int O_TPP   = 163840;
constexpr int O_TPTN  = 180224;
constexpr int O_TPPN  = 196608;

constexpr float GUARD = 1.4999f;
} // namespace

__device__ __forceinline__ unsigned long long shfl_xor_u64(unsigned long long v, int m) {
    unsigned lo = (unsigned)v, hi = (unsigned)(v >> 32);
    lo = __shfl_xor(lo, m); hi = __shfl_xor(hi, m);
    return ((unsigned long long)hi << 32) | lo;
}

// position from raw input + cell index — bit-identical everywhere (contract off,
// lattice constants 25/32 and 3/4 are exactly representable)
__device__ __forceinline__ float3 cellpos(float4 p, int n) {
#pragma clang fp contract(off)
    float fx = (float)(n >> 7), fy = (float)((n >> 2) & 31), fz = (float)(n & 3);
    float3 r;
    r.x = (p.x + fx) * 0.78125f;
    r.y = (p.y + fy) * 0.78125f;
    r.z = (p.z + fz) * 0.75f;
    return r;
}
__device__ __forceinline__ float dist2(float3 a, float3 b) {
#pragma clang fp contract(off)
    float dx = a.x - b.x, dy = a.y - b.y, dz = a.z - b.z;
    float d2 = dx * dx + dy * dy;
    return d2 + dz * dz;   // numpy sum order: (x+y)+z
}

// exact restrain count of slice-local point pn, reading GLOBAL pred.
// Only used by the never-taken exact fallback.
__device__ __forceinline__ unsigned restrain_of(const float4* __restrict__ pred,
                                                int base4, int pn, float se) {
#pragma clang fp contract(off)
    float4 p = pred[base4 + pn * 2];
    if (!(p.w > 0.5f)) return 0u;
    float3 pj = cellpos(p, pn);
    int gx = pn >> 7, gy = (pn >> 2) & 31;
    unsigned c = 0;
    for (int q = 0; q < 9; ++q) {
        int nx = gx + q / 3 - 1, ny = gy + q % 3 - 1;
        if ((unsigned)nx > 31u || (unsigned)ny > 31u) continue;
        int nb = nx * 128 + ny * 4;
#pragma unroll
        for (int nz = 0; nz < 4; ++nz) {
            int ni = nb + nz;
            float4 pi = pred[base4 + ni * 2];
            float3 qi = cellpos(pi, ni);
            float d2 = dist2(pj, qi);
            bool prec = (pi.w > p.w) || ((pi.w == p.w) && (ni < pn));
            if ((pi.w > 0.5f) && (d2 < se) && prec) c++;
        }
    }
    return c;
}

// exact keep decision of slice-local point k (suppression on top of restrain),
// reading GLOBAL pred. Only called from the rare fallback path.
__device__ __noinline__ bool keep_of(const float4* __restrict__ pred,
                                     int base4, int k, float se) {
#pragma clang fp contract(off)
    float4 p = pred[base4 + k * 2];
    if (!(p.w > 0.5f)) return false;
    float3 pj = cellpos(p, k);
    int gx = k >> 7, gy = (k >> 2) & 31;
    for (int q = 0; q < 9; ++q) {
        int nx = gx + q / 3 - 1, ny = gy + q % 3 - 1;
        if ((unsigned)nx > 31u || (unsigned)ny > 31u) continue;
        int nb = nx * 128 + ny * 4;
        for (int nz = 0; nz < 4; ++nz) {
            int ni = nb + nz;
            float4 pi = pred[base4 + ni * 2];
            float3 qi = cellpos(pi, ni);
            float d2 = dist2(pj, qi);
            bool prec = (pi.w > p.w) || ((pi.w == p.w) && (ni < k));
            if ((pi.w > 0.5f) && (d2 < se) && prec &&
                restrain_of(pred, base4, ni, se) == 0u)
                return false;
        }
    }
    return true;
}

// ---------------------------------------------------------------------------
// Single fused kernel. One block per (s, gx-pair, gy-eighth):
// 4*16*8 = 512 blocks, 512 threads -> fully resident at 2 blocks/CU.
// Interior: 2 gx cols x 4 gy x 4 z = 32 rows/block.
// Stage : pred window [gx0-4,gx0+5] x [gy0-4,gy0+7] x z (10x12x4=480) -> LDS,
//         position pre-projected, conf in .w; OOB cells get conf=-1 which
//         every later predicate rejects, so phase loops are bounds-check-free.
// Phase A: restrain over [gx0-3..+4]x[gy0-3..+6] (8x10x4=320) -> LDS uchar
//          (z+-1 comps only).
// Phase B: keep over [gx0-2..+3]x[gy0-2..+5] (6x8x4=192) -> LDS uchar (z+-1);
//          interior 32 rows write p_pos / mask_p / keep.
// Phase C: match (both variants) for the 32 interior rows, 16 threads/row,
//          5x5 xy window x full z from LDS, inline exact (global) fallback.
__global__ void __launch_bounds__(512, 4) k_all(const float4* __restrict__ pred,
                                                const float4* __restrict__ tgt,
                                                float* __restrict__ out,
                                                float s0, float s1) {
#pragma clang fp contract(off)
    __shared__ float4 pp[10 * 12 * 4];            // (pos.xyz, conf) 7680 B
    __shared__ unsigned char restr[8 * 10 * 4];   // 320
    __shared__ unsigned char keepl[6 * 8 * 4];    // 192
    int bid = blockIdx.x;
    int gy0 = (bid & 7) << 2, gx0 = ((bid >> 3) & 15) << 1, s = bid >> 7;
    int b = s >> 1, e = s & 1;
    int base4 = b * 8192 + e;
    float se = (s & 1) ? s1 : s0;
    int t = (int)threadIdx.x;

    // phase-C row of this thread; tgt prefetched at entry so its global
    // latency hides under stage/A/B.
    int rr = t >> 4, hh = t & 15;
    int gxl_c = rr >> 4, rem_c = rr & 15;
    int gyy_c = rem_c >> 2, z_c = rem_c & 3;
    int n_c = ((gx0 + gxl_c) << 7) + ((gy0 + gyy_c) << 2) + z_c;
    float4 t4 = tgt[base4 + n_c * 2];

    // ---- stage pred window -> LDS (1 load for t<480)
    if (t < 480) {
        int rx = t / 48, rem = t - rx * 48, ry = rem >> 2, z = rem & 3;
        int px = gx0 + rx - 4, py = gy0 + ry - 4;
        float4 v = {0.0f, 0.0f, 0.0f, -1.0f};
        if ((unsigned)px < 32u && (unsigned)py < 32u) {
            int pn = px * 128 + py * 4 + z;
            float4 p = pred[base4 + pn * 2];
            float3 c = cellpos(p, pn);
            v.x = c.x; v.y = c.y; v.z = c.z; v.w = p.w;
        }
        pp[t] = v;
    }
    __syncthreads();

    // ---- phase A: restrain halo (320 pts, 1/thread), z+-1 comps
    if (t < 320) {
        int ax = t / 40, rem = t - ax * 40, ay = rem >> 2, z = rem & 3;
        int px = gx0 + ax - 3, py = gy0 + ay - 3;
        float4 p = pp[((ax + 1) * 12 + (ay + 1)) * 4 + z];
        unsigned c = 0;
        if (p.w > 0.5f) {                          // OOB center: conf=-1 -> skip
            int pn = px * 128 + py * 4 + z;
            float3 pj = {p.x, p.y, p.z};
#pragma unroll
            for (int q = 0; q < 9; ++q) {
                int dx = q / 3 - 1, dy = q % 3 - 1;
                int nb = (px + dx) * 128 + (py + dy) * 4;
                const float4* pc = &pp[((ax + 1 + dx) * 12 + (ay + 1 + dy)) * 4];
#pragma unroll
                for (int dz = -1; dz <= 1; ++dz) {
                    int nz = z + dz;
                    int nzc = nz < 0 ? 0 : (nz > 3 ? 3 : nz);
                    float4 pi = pc[nzc];
                    int ni = nb + nz;
                    float3 qi = {pi.x, pi.y, pi.z};
                    float d2 = dist2(pj, qi);
                    bool zok = (unsigned)nz < 4u;
                    bool prec = (pi.w > p.w) || ((pi.w == p.w) && (ni < pn));
                    if (zok && (pi.w > 0.5f) && (d2 < se) && prec) c++;
                }
            }
        }
        restr[t] = (unsigned char)c;               // max 27, fits uchar
    }
    __syncthreads();

    // ---- phase B: keep halo (192 pts, 1/thread), z+-1; interior writes out
    if (t < 192) {
        int kx = t / 32, rem = t - kx * 32, ky = rem >> 2, z = rem & 3;
        int px = gx0 + kx - 2, py = gy0 + ky - 2;
        float4 p = pp[((kx + 2) * 12 + (ky + 2)) * 4 + z];
        bool valid = p.w > 0.5f;
        int pn = px * 128 + py * 4 + z;
        unsigned any = 0;
        if (valid) {
            float3 pj = {p.x, p.y, p.z};
#pragma unroll
            for (int q = 0; q < 9; ++q) {
                int dx = q / 3 - 1, dy = q % 3 - 1;
                int nb = (px + dx) * 128 + (py + dy) * 4;
                const float4* pc = &pp[((kx + 2 + dx) * 12 + (ky + 2 + dy)) * 4];
                const unsigned char* lr =
                    &restr[((kx + 1 + dx) * 10 + (ky + 1 + dy)) * 4];
#pragma unroll
                for (int dz = -1; dz <= 1; ++dz) {
                    int nz = z + dz;
                    int nzc = nz < 0 ? 0 : (nz > 3 ? 3 : nz);
                    float4 pi = pc[nzc];
                    int ni = nb + nz;
                    float3 qi = {pi.x, pi.y, pi.z};
                    float d2 = dist2(pj, qi);
                    bool zok = (unsigned)nz < 4u;
                    bool prec = (pi.w > p.w) || ((pi.w == p.w) && (ni < pn));
                    if (zok && (pi.w > 0.5f) && (lr[nzc] == 0) && (d2 < se) && prec)
                        any = 1u;
                }
            }
        }
        bool keep = valid && (any == 0);
        keepl[t] = keep ? 1 : 0;
        if (kx >= 2 && kx < 4 && ky >= 2 && ky < 6) {  // interior: in-bounds
            int row = s * NPT + pn;
            out[O_PPOS + row * 3 + 0] = p.x;
            out[O_PPOS + row * 3 + 1] = p.y;
            out[O_PPOS + row * 3 + 2] = p.z;
            out[O_MASKP + row] = valid ? 1.0f : 0.0f;
            out[O_KEEP + row]  = keep ? 1.0f : 0.0f;
        }
    }
    __syncthreads();

    // ---- phase C: match, 32 rows x 16 threads
    int gxl = gxl_c, gyy = gyy_c, h = hh;
    int gx = gx0 + gxl, gy = gy0 + gyy;
    int n = n_c;
    int row = s * NPT + n;
    float3 tj = cellpos(t4, n);
    bool tv = t4.w > 0.5f;
    if (h == 0) {
        out[O_TPOS + row * 3 + 0] = tj.x;
        out[O_TPOS + row * 3 + 1] = tj.y;
        out[O_TPOS + row * 3 + 2] = tj.z;
        out[O_MASKT + row] = tv ? 1.0f : 0.0f;
    }
    if (!tv) {   // group-uniform early out (all-inf row -> masks 0, idx 0)
        if (h == 0) {
            out[O_TPT + row] = 0.0f; out[O_TPTN + row] = 0.0f;
            out[O_TPP + row] = 0.0f; out[O_TPPN + row] = 0.0f;
        }
        return;
    }
    unsigned long long bs = ~0ull, bn = ~0ull;
    unsigned as_ = 0, an_ = 0;
#pragma unroll
    for (int pass = 0; pass < 2; ++pass) {
        int q = pass * 16 + h;                     // pass0: h, pass1: h+16 (h<9)
        if (q > 24) continue;
        int dx = q / 5 - 2, dy = q % 5 - 2;
        int nb = (gx + dx) * 128 + (gy + dy) * 4;
        const float4* pc = &pp[((gxl + dx + 4) * 12 + (gyy + dy + 4)) * 4];
        const unsigned char* lk = &keepl[((gxl + dx + 2) * 8 + (gyy + dy + 2)) * 4];
#pragma unroll
        for (int nz = 0; nz < 4; ++nz) {
            float4 pi = pc[nz];
            int ni = nb + nz;
            float3 qi = {pi.x, pi.y, pi.z};
            float d2 = dist2(tj, qi);
            float dist = sqrtf(d2);
            unsigned long long enc =
                ((unsigned long long)__float_as_uint(dist) << 32) | (unsigned)ni;
            if (pi.w > 0.5f) { if (enc < bs) bs = enc; if (d2 < se) as_ = 1u; }
            if (lk[nz]) { if (enc < bn) bn = enc; if (d2 < se) an_ = 1u; }
        }
    }
    for (int m = 1; m < 16; m <<= 1) {             // combine across the 16-group
        unsigned long long o = shfl_xor_u64(bs, m); if (o < bs) bs = o;
        o = shfl_xor_u64(bn, m); if (o < bn) bn = o;
        as_ |= __shfl_xor(as_, m);
        an_ |= __shfl_xor(an_, m);
    }
    // empty best -> hi word 0xFFFFFFFF = NaN -> compare false -> fallback
    bool acc_s = __uint_as_float((unsigned)(bs >> 32)) < GUARD;
    bool acc_n = __uint_as_float((unsigned)(bn >> 32)) < GUARD;
    if (!(acc_s && acc_n)) {
        // exact full-row fallback by this 16-group (p ~ 1e-11, never observed;
        // bit-equal to window result when the window would have accepted).
        unsigned long long fs = ~0ull, fn = ~0ull;
        for (int k = h; k < NPT; k += 16) {
            float4 pi = pred[base4 + k * 2];
            float3 qi = cellpos(pi, k);
            float d2 = dist2(tj, qi);
            float dist = sqrtf(d2);
            unsigned long long enc =
                ((unsigned long long)__float_as_uint(dist) << 32) | (unsigned)k;
            if (pi.w > 0.5f && enc < fs) fs = enc;
            if (enc < fn && keep_of(pred, base4, k, se)) fn = enc;
        }
        for (int m = 1; m < 16; m <<= 1) {
            unsigned long long o = shfl_xor_u64(fs, m); if (o < fs) fs = o;
            o = shfl_xor_u64(fn, m); if (o < fn) fn = o;
        }
        bs = fs; bn = fn;
    }
    if (h == 0) {
        out[O_TPT + row]  = as_ ? 1.0f : 0.0f;
        out[O_TPTN + row] = an_ ? 1.0f : 0.0f;
        out[O_TPP + row]  = (float)((bs == ~0ull) ? 0u : (unsigned)(bs & 0xffffffffull));
        out[O_TPPN + row] = (float)((bn == ~0ull) ? 0u : (unsigned)(bn & 0xffffffffull));
    }
}

// ---------------------------------------------------------------------------
// host: smallest f with sqrtf(f) >= t, so (d2 < f) <=> (sqrtf(d2) < t) bit-exactly.
static float sq_boundary(float t) {
    float f = (float)((double)t * (double)t);
    while (sqrtf(f) >= t) f = nextafterf(f, 0.0f);
    while (sqrtf(f) < t)  f = nextafterf(f, __builtin_inff());
    return f;
}

extern "C" void kernel_launch(void* const* d_in, const int* in_sizes, int n_in,
                              void* d_out, int out_size, void* d_ws, size_t ws_size,
                              hipStream_t stream) {
    (void)in_sizes; (void)n_in; (void)out_size; (void)d_ws; (void)ws_size;
    const float4* pred = (const float4*)d_in[0];
    const float4* tgt  = (const float4*)d_in[1];
    float* out = (float*)d_out;

    float s0 = sq_boundary(0.74f);    // ELE_D[0]
    float s1 = sq_boundary(0.528f);   // ELE_D[1]

    k_all<<<dim3(512), dim3(512), 0, stream>>>(pred, tgt, out, s0, s1);
}